// Round 6
// baseline (99.254 us; speedup 1.0000x reference)
//
#include <hip/hip_runtime.h>
#include <math.h>

// GptOssTopKRouter on MI355X — round 6.
// X[16384,2880] fp32 @ W[32,2880]^T + b -> top4 -> softmax -> scatter.
//
// Round-5 post-mortem: pipes (FMA 46k, LDS 52k, TCP 29k cyc/CU) each ~21us
// but measured 57us -> latency-bound at 2 waves/SIMD (acc=128 VGPR blocked
// occupancy). Round 6: 8-token waves -> acc = 8t x 8e = 64 VGPR, 256-thread
// blocks, grid 1024, 4 blocks/CU = 16 waves/CU = 4/SIMD.
//   - X staging: ONE global_load_dwordx4 per chunk per wave (8tx32h = 1KB),
//     4 scalar ds_writes (write2-pairable) + 4 ds_read_b128, 1-bit XOR
//     col-swizzle ((h>>3)&1)<<2 -> all LDS ops <=2/bank (free).
//   - W per-lane coalesced from WT[2880][32], depth-1 register prefetch.
//   - no barriers in the main loop (wave-private tiles).
// wave = (tg in 0..1 [8 tokens], half in 0..1 [1440 h]); chunk = 32 h.

#define HIDDEN 2880
#define NE 32
#define TOPK 4
#define TPB 16            // tokens per block
#define HHALF 1440        // h per half
#define CH 32             // h per chunk
#define NCH 45            // chunks per half
#define ROWP 12           // padded LDS row: 8 t + 4 pad (48 B)
#define TILE (CH * ROWP)  // 384 floats per buffer
#define PST 36            // part row stride

__global__ void transpose_w_kernel(const float* __restrict__ w, float* __restrict__ wt) {
    int i = blockIdx.x * 256 + threadIdx.x;
    if (i < NE * HIDDEN) {
        int e = i / HIDDEN;
        int h = i - e * HIDDEN;
        wt[h * NE + e] = w[i];
    }
}

#define FMA4(a, xs, w4) do {                         \
    (a).x = fmaf((xs), (w4).x, (a).x);               \
    (a).y = fmaf((xs), (w4).y, (a).y);               \
    (a).z = fmaf((xs), (w4).z, (a).z);               \
    (a).w = fmaf((xs), (w4).w, (a).w); } while (0)

__device__ __forceinline__ float4 selred(float4 lo, float4 hi, int sel, int mask) {
    float gx = sel ? lo.x : hi.x, kx = sel ? hi.x : lo.x;
    float gy = sel ? lo.y : hi.y, ky = sel ? hi.y : lo.y;
    float gz = sel ? lo.z : hi.z, kz = sel ? hi.z : lo.z;
    float gw = sel ? lo.w : hi.w, kw = sel ? hi.w : lo.w;
    return make_float4(kx + __shfl_xor(gx, mask), ky + __shfl_xor(gy, mask),
                       kz + __shfl_xor(gz, mask), kw + __shfl_xor(gw, mask));
}

__global__ __launch_bounds__(256, 4)
void router_kernel(const float* __restrict__ x,
                   const float* __restrict__ wt,
                   const float* __restrict__ bias,
                   float* __restrict__ out_scores,
                   float* __restrict__ out_idx)
{
    __shared__ float xt[4 * 2 * TILE];        // 12 KB: per-wave double-buffered tiles
    __shared__ float part[2][TPB][PST];       // 4.6 KB: h-half partials

    const int tid  = threadIdx.x;
    const int lane = tid & 63;
    const int w    = tid >> 6;
    const int tg   = w & 1;           // token group (8 tokens)
    const int half = w >> 1;          // h half
    const int eg   = lane & 3;        // expert group (8 experts)
    const int h16  = lane >> 2;       // h position within 16
    const int srow = lane >> 3;       // staging: token index (0..7)
    const int scol = (lane & 7) * 4;  // staging: h base within chunk
    const int tok0 = blockIdx.x * TPB + tg * 8;

    // staging source: lane reads float4 x[tok0+srow][hb + scol .. +3]
    const float* xs = x + (size_t)(tok0 + srow) * HIDDEN + half * HHALF + scol;
    // weights: lane's 8 experts at its h16 rows of WT
    const float* wp = wt + (size_t)(half * HHALF + h16) * NE + eg * 8;

    float* xtw  = xt + w * (2 * TILE);
    float* buf0 = xtw;
    float* buf1 = xtw + TILE;

    float4 acc[16];                   // [t 0..7][e-part 0..1] = 64 VGPR
#pragma unroll
    for (int i = 0; i < 16; ++i) acc[i] = make_float4(0.f, 0.f, 0.f, 0.f);

    // 1-bit XOR col swizzle: constant over a float4's 4 rows (scol%8 in {0,4})
    const int wcs = srow ^ (((scol >> 3) & 1) << 2);
    const int qv  = ((h16 >> 3) & 1) << 2;   // read-side swizzle (same for s=0,1)

#define XLOAD(g, c) do {                                                          \
    g = *(const float4*)(xs + (size_t)(c) * CH);                                  \
} while (0)

#define WLOAD(wv, c) do { _Pragma("unroll")                                       \
    for (int s = 0; s < 2; ++s) {                                                 \
        wv[s][0] = *(const float4*)(wp + ((size_t)(c) * CH + s * 16) * NE);       \
        wv[s][1] = *(const float4*)(wp + ((size_t)(c) * CH + s * 16) * NE + 4);   \
    } } while (0)

#define STAGE(buf, g) do {                                                        \
    float* p_ = (buf) + scol * ROWP + wcs;                                        \
    p_[0]        = g.x;                                                           \
    p_[ROWP]     = g.y;                                                           \
    p_[2 * ROWP] = g.z;                                                           \
    p_[3 * ROWP] = g.w;                                                           \
} while (0)

#define COMPUTE(buf, wv) do { _Pragma("unroll")                                   \
    for (int s = 0; s < 2; ++s) {                                                 \
        const int S = s * 16 + h16;                                               \
        _Pragma("unroll")                                                         \
        for (int tq = 0; tq < 2; ++tq) {                                          \
            const float4 xv = *(const float4*)((buf) + S * ROWP + ((tq * 4) ^ qv)); \
            FMA4(acc[(tq*4+0)*2+0], xv.x, wv[s][0]); FMA4(acc[(tq*4+0)*2+1], xv.x, wv[s][1]); \
            FMA4(acc[(tq*4+1)*2+0], xv.y, wv[s][0]); FMA4(acc[(tq*4+1)*2+1], xv.y, wv[s][1]); \
            FMA4(acc[(tq*4+2)*2+0], xv.z, wv[s][0]); FMA4(acc[(tq*4+2)*2+1], xv.z, wv[s][1]); \
            FMA4(acc[(tq*4+3)*2+0], xv.w, wv[s][0]); FMA4(acc[(tq*4+3)*2+1], xv.w, wv[s][1]); \
        } } } while (0)

    float4 xa, xb;
    float4 wa[2][2], wb[2][2];

    XLOAD(xa, 0); WLOAD(wa, 0);
#pragma unroll 1
    for (int cc = 0; cc < NCH / 2; ++cc) {    // 22 pairs + tail (NCH=45)
        const int c0 = 2 * cc;
        XLOAD(xb, c0 + 1); WLOAD(wb, c0 + 1);
        STAGE(buf0, xa); COMPUTE(buf0, wa);
        if (c0 + 2 < NCH) { XLOAD(xa, c0 + 2); WLOAD(wa, c0 + 2); }
        STAGE(buf1, xb); COMPUTE(buf1, wb);
    }
    STAGE(buf0, xa); COMPUTE(buf0, wa);       // tail chunk 44

#undef XLOAD
#undef WLOAD
#undef STAGE
#undef COMPUTE
#undef FMA4

    // ---- in-wave halving butterfly over h16 (lane bits 2..5) ----
    const int s1 = (lane >> 2) & 1, s2 = (lane >> 3) & 1;
    const int s3 = (lane >> 4) & 1, s4 = (lane >> 5) & 1;

    float4 na[8];
#pragma unroll
    for (int t = 0; t < 4; ++t)
#pragma unroll
        for (int p = 0; p < 2; ++p)
            na[t*2+p] = selred(acc[t*2+p], acc[(t+4)*2+p], s1, 4);
    float4 nb[4];
#pragma unroll
    for (int t = 0; t < 2; ++t)
#pragma unroll
        for (int p = 0; p < 2; ++p)
            nb[t*2+p] = selred(na[t*2+p], na[(t+2)*2+p], s2, 8);
    float4 nc[2];
#pragma unroll
    for (int p = 0; p < 2; ++p)
        nc[p] = selred(nb[p], nb[2+p], s3, 16);
    float4 nd = selred(nc[0], nc[1], s4, 32);

    const int tt = s1 * 4 + s2 * 2 + s3;      // token owned by this lane
    *reinterpret_cast<float4*>(&part[half][tg * 8 + tt][eg * 8 + s4 * 4]) = nd;
    __syncthreads();

    // ---- top-4 + softmax, one lane per token ----
    float* scorebuf = xt;                     // reuse staging LDS
    if (tid < TPB) {
        float lg[NE];
#pragma unroll
        for (int e = 0; e < NE; ++e)
            lg[e] = part[0][tid][e] + part[1][tid][e] + bias[e];

        float vals[TOPK]; int idxs[TOPK]; unsigned chosen = 0u;
#pragma unroll
        for (int k = 0; k < TOPK; ++k) {
            float m = -INFINITY; int mi = 0;
#pragma unroll
            for (int e = 0; e < NE; ++e) {
                const bool take = (((chosen >> e) & 1u) == 0u) && (lg[e] > m);
                m  = take ? lg[e] : m;
                mi = take ? e : mi;
            }
            vals[k] = m; idxs[k] = mi; chosen |= (1u << (unsigned)mi);
        }
        const float mx = vals[0];
        float p[TOPK]; float sum = 0.f;
#pragma unroll
        for (int k = 0; k < TOPK; ++k) { p[k] = __expf(vals[k] - mx); sum += p[k]; }
        const float inv = 1.0f / sum;
#pragma unroll
        for (int e = 0; e < NE; ++e) {
            float v = 0.f;
#pragma unroll
            for (int k = 0; k < TOPK; ++k) v = (e == idxs[k]) ? p[k] * inv : v;
            scorebuf[tid * 33 + e] = v;       // stride 33: conflict-free stash
        }
        const int t = blockIdx.x * TPB + tid;
        float4 iv = make_float4((float)idxs[0], (float)idxs[1], (float)idxs[2], (float)idxs[3]);
        *reinterpret_cast<float4*>(out_idx + (size_t)t * TOPK) = iv;
    }
    __syncthreads();

    // coalesced score store: 512 floats, 256 threads x float2
    {
        const int f = tid * 2;
        const int t = f >> 5, e = f & 31;
        float2 v = make_float2(scorebuf[t * 33 + e], scorebuf[t * 33 + e + 1]);
        *reinterpret_cast<float2*>(out_scores + (size_t)blockIdx.x * TPB * NE + f) = v;
    }
}

extern "C" void kernel_launch(void* const* d_in, const int* in_sizes, int n_in,
                              void* d_out, int out_size, void* d_ws, size_t ws_size,
                              hipStream_t stream)
{
    const float* x = (const float*)d_in[0];
    const float* w = (const float*)d_in[1];
    const float* b = (const float*)d_in[2];
    const int T = in_sizes[0] / HIDDEN;            // 16384 tokens

    float* wt = (float*)d_ws;                      // [2880][32] = 368.6 KB scratch
    float* out        = (float*)d_out;
    float* out_scores = out;                       // [T, 32]
    float* out_idx    = out + (size_t)T * NE;      // [T, 4] as fp32 values

    transpose_w_kernel<<<dim3((NE * HIDDEN + 255) / 256), dim3(256), 0, stream>>>(w, wt);
    router_kernel<<<dim3(T / TPB), dim3(256), 0, stream>>>(x, wt, b, out_scores, out_idx);
}

// Round 7
// 52.773 us; speedup vs baseline: 1.8808x; 1.8808x over previous
//
#include <hip/hip_runtime.h>
#include <math.h>

// GptOssTopKRouter on MI355X — round 7: split-bf16 MFMA.
// logits = X[16384,2880] @ W^T + b computed as 6 bf16 MFMA passes:
//   X = xh+xm+xl (3 bf16 trunc-split terms), W likewise; passes
//   hh + hm + mh + hl + mm + lh accumulate in one fp32 MFMA acc.
//   Dropped terms ~2^-24 -> logit err ~1e-7 (better than fp32-tree reorder).
// Structure: 512-thr blocks, grid 256 (64 tok/block); 8 waves = 4 M-tiles x
// 2 K-halves (1440 each). Per chunk (96 k): wave loads its 16 rows fp32
// (coalesced dwordx4), splits to 3 bf16 tiles in LDS (XOR-swizzled,
// conflict-free), then 3 k-steps x 12 MFMA (16x16x32_bf16) with B-frags
// loaded per-lane from a pre-split, fragment-layout W (553 KB in d_ws).
// Wave-private LDS rows + in-order per-wave LDS => NO barriers in main loop.

#define HIDDEN 2880
#define NE 32
#define TOPK 4
#define TPB 64
#define KC 96            // k per chunk
#define NCHW 15          // chunks per K-half (1440/96)

typedef __attribute__((ext_vector_type(8))) short bf16x8;
typedef __attribute__((ext_vector_type(4))) float f32x4;

#define MFMA(a, b, c) __builtin_amdgcn_mfma_f32_16x16x32_bf16((a), (b), (c), 0, 0, 0)

// trunc-split fp32 -> 3 bf16 bit patterns (hi, mid, lo)
__device__ __forceinline__ void split3(float x, unsigned& h, unsigned& m, unsigned& l) {
    unsigned u = __float_as_uint(x);
    h = u >> 16;
    float r = x - __uint_as_float(u & 0xffff0000u);      // exact (Sterbenz)
    unsigned ur = __float_as_uint(r);
    m = ur >> 16;
    float r2 = r - __uint_as_float(ur & 0xffff0000u);    // exact
    l = __float_as_uint(r2) >> 16;
}

// Pre-kernel: W[32][2880] fp32 -> WB[3 ver][90 kstep][2 ct][512] bf16 in
// exact B-fragment order: element (l, j) = split_ver(W[ct*16+(l&15)][ks*32+(l>>4)*8+j])
__global__ void wb_kernel(const float* __restrict__ w, unsigned short* __restrict__ wb) {
    int i = blockIdx.x * 256 + threadIdx.x;
    if (i >= 3 * 90 * 2 * 512) return;
    int j = i & 7;
    int t = i >> 3;
    int l = t & 63;  t >>= 6;
    int ct = t & 1;  t >>= 1;
    int ks = t % 90;
    int ver = t / 90;
    int e = ct * 16 + (l & 15);
    int k = ks * 32 + (l >> 4) * 8 + j;
    unsigned h, m, lo;
    split3(w[e * HIDDEN + k], h, m, lo);
    wb[i] = (unsigned short)(ver == 0 ? h : (ver == 1 ? m : lo));
}

__global__ __launch_bounds__(512, 1)
void router_kernel(const float* __restrict__ x,
                   const unsigned short* __restrict__ wb,
                   const float* __restrict__ bias,
                   float* __restrict__ out_scores,
                   float* __restrict__ out_idx)
{
    __shared__ unsigned short xs[2][3][64][128];   // 96 KB: [khalf][ver][row][padded k]
    __shared__ float part[2][64][33];              // 16.9 KB: K-half C partials

    const int tid  = threadIdx.x;
    const int lane = tid & 63;
    const int w    = tid >> 6;
    const int wm   = w & 3;          // M-tile (16 tokens)
    const int kh   = w >> 2;         // K-half (1440)

    // ---- staging geometry: lane covers row rl=lane>>2, float4-quad kq0=lane&3 ----
    const int rl  = lane >> 2;       // 0..15 local row
    const int kq0 = lane & 3;        // float4 index base
    const float* xp = x + (size_t)(blockIdx.x * TPB + wm * 16 + rl) * HIDDEN + kh * 1440;

    unsigned short* wrow_h = &xs[kh][0][wm * 16 + rl][0];
    unsigned short* wrow_m = &xs[kh][1][wm * 16 + rl][0];
    unsigned short* wrow_l = &xs[kh][2][wm * 16 + rl][0];
    const int r7w = rl & 7;

    // ---- A-fragment geometry: row = lane&15, k-block = lane>>4 ----
    const unsigned short* arow_h = &xs[kh][0][wm * 16 + (lane & 15)][0];
    const unsigned short* arow_m = &xs[kh][1][wm * 16 + (lane & 15)][0];
    const unsigned short* arow_l = &xs[kh][2][wm * 16 + (lane & 15)][0];
    const int r7a = lane & 7;        // (wm*16+(lane&15))&7
    const int kb  = lane >> 4;       // 0..3

    f32x4 acc0 = {0.f, 0.f, 0.f, 0.f};
    f32x4 acc1 = {0.f, 0.f, 0.f, 0.f};

    float4 xf[6], xg[6];
#pragma unroll
    for (int s = 0; s < 6; ++s) xf[s] = *(const float4*)(xp + (kq0 + 4 * s) * 4);

#pragma unroll 1
    for (int c = 0; c < NCHW; ++c) {
        if (c + 1 < NCHW) {
#pragma unroll
            for (int s = 0; s < 6; ++s)
                xg[s] = *(const float4*)(xp + (c + 1) * KC + (kq0 + 4 * s) * 4);
        }
        // ---- convert + stage (swizzled b64 writes; wave-private rows) ----
#pragma unroll
        for (int s = 0; s < 6; ++s) {
            const int kq  = kq0 + 4 * s;                  // float4 index 0..23
            const int q   = kq >> 1;                      // 16B slot 0..11
            const int off = 8 * (q ^ r7w) + (kq & 1) * 4; // ushort offset
            unsigned h0, m0, l0, h1, m1, l1, h2, m2, l2, h3, m3, l3;
            split3(xf[s].x, h0, m0, l0);
            split3(xf[s].y, h1, m1, l1);
            split3(xf[s].z, h2, m2, l2);
            split3(xf[s].w, h3, m3, l3);
            *(uint2*)(wrow_h + off) = make_uint2(h0 | (h1 << 16), h2 | (h3 << 16));
            *(uint2*)(wrow_m + off) = make_uint2(m0 | (m1 << 16), m2 | (m3 << 16));
            *(uint2*)(wrow_l + off) = make_uint2(l0 | (l1 << 16), l2 | (l3 << 16));
        }
        // ---- 3 k-steps x (3 A ds_read_b128 + 6 B dwordx4 + 12 MFMA) ----
        const int ksg = kh * 45 + c * 3;
#pragma unroll
        for (int s = 0; s < 3; ++s) {
            const int aoff = 8 * ((kb + 4 * s) ^ r7a);
            bf16x8 ah = *(const bf16x8*)(arow_h + aoff);
            bf16x8 am = *(const bf16x8*)(arow_m + aoff);
            bf16x8 al = *(const bf16x8*)(arow_l + aoff);
            const size_t bb = (size_t)(ksg + s) * 1024 + lane * 8;  // [ks][ct][512]
            bf16x8 bh0 = *(const bf16x8*)(wb + bb);
            bf16x8 bh1 = *(const bf16x8*)(wb + bb + 512);
            bf16x8 bm0 = *(const bf16x8*)(wb + 92160 + bb);
            bf16x8 bm1 = *(const bf16x8*)(wb + 92160 + bb + 512);
            bf16x8 bl0 = *(const bf16x8*)(wb + 184320 + bb);
            bf16x8 bl1 = *(const bf16x8*)(wb + 184320 + bb + 512);
            acc0 = MFMA(ah, bh0, acc0);
            acc0 = MFMA(ah, bm0, acc0);
            acc0 = MFMA(am, bh0, acc0);
            acc0 = MFMA(ah, bl0, acc0);
            acc0 = MFMA(am, bm0, acc0);
            acc0 = MFMA(al, bh0, acc0);
            acc1 = MFMA(ah, bh1, acc1);
            acc1 = MFMA(ah, bm1, acc1);
            acc1 = MFMA(am, bh1, acc1);
            acc1 = MFMA(ah, bl1, acc1);
            acc1 = MFMA(am, bm1, acc1);
            acc1 = MFMA(al, bh1, acc1);
        }
#pragma unroll
        for (int s = 0; s < 6; ++s) xf[s] = xg[s];
    }

    // ---- C fragments -> part (m89-verified C/D layout: col=lane&15, row=(lane>>4)*4+j) ----
    {
        const int col = lane & 15;
        const int rb  = (lane >> 4) * 4;
#pragma unroll
        for (int j = 0; j < 4; ++j) {
            part[kh][wm * 16 + rb + j][col]      = acc0[j];
            part[kh][wm * 16 + rb + j][16 + col] = acc1[j];
        }
    }
    __syncthreads();

    // ---- top-4 + softmax, one lane per token ----
    float* sb = &part[0][0][0];                    // reused as score stash
    if (tid < TPB) {
        float lg[NE];
#pragma unroll
        for (int e = 0; e < NE; ++e)
            lg[e] = part[0][tid][e] + part[1][tid][e] + bias[e];

        float vals[TOPK]; int idxs[TOPK]; unsigned chosen = 0u;
#pragma unroll
        for (int k = 0; k < TOPK; ++k) {
            float m = -INFINITY; int mi = 0;
#pragma unroll
            for (int e = 0; e < NE; ++e) {
                const bool take = (((chosen >> e) & 1u) == 0u) && (lg[e] > m);
                m  = take ? lg[e] : m;
                mi = take ? e : mi;
            }
            vals[k] = m; idxs[k] = mi; chosen |= (1u << (unsigned)mi);
        }
        const float mx = vals[0];
        float p[TOPK]; float sum = 0.f;
#pragma unroll
        for (int k = 0; k < TOPK; ++k) { p[k] = __expf(vals[k] - mx); sum += p[k]; }
        const float inv = 1.0f / sum;
#pragma unroll
        for (int e = 0; e < NE; ++e) {
            float v = 0.f;
#pragma unroll
            for (int k = 0; k < TOPK; ++k) v = (e == idxs[k]) ? p[k] * inv : v;
            sb[tid * 33 + e] = v;                  // own row only: no cross-thread hazard
        }
        const int t = blockIdx.x * TPB + tid;
        float4 iv = make_float4((float)idxs[0], (float)idxs[1], (float)idxs[2], (float)idxs[3]);
        *reinterpret_cast<float4*>(out_idx + (size_t)t * TOPK) = iv;
    }
    __syncthreads();

    // ---- coalesced score store: 2048 floats, 512 threads x float4 ----
    {
        const int f = tid * 4;
        const int t = f >> 5, e = f & 31;
        float4 v = make_float4(sb[t * 33 + e], sb[t * 33 + e + 1],
                               sb[t * 33 + e + 2], sb[t * 33 + e + 3]);
        *reinterpret_cast<float4*>(out_scores + (size_t)blockIdx.x * TPB * NE + f) = v;
    }
}

extern "C" void kernel_launch(void* const* d_in, const int* in_sizes, int n_in,
                              void* d_out, int out_size, void* d_ws, size_t ws_size,
                              hipStream_t stream)
{
    const float* x = (const float*)d_in[0];
    const float* w = (const float*)d_in[1];
    const float* b = (const float*)d_in[2];
    const int T = in_sizes[0] / HIDDEN;            // 16384 tokens

    unsigned short* wbuf = (unsigned short*)d_ws;  // 3*90*2*512 bf16 = 553 KB
    float* out        = (float*)d_out;
    float* out_scores = out;                       // [T, 32]
    float* out_idx    = out + (size_t)T * NE;      // [T, 4] as fp32 values

    wb_kernel<<<dim3((3 * 90 * 2 * 512 + 255) / 256), dim3(256), 0, stream>>>(w, wbuf);
    router_kernel<<<dim3(T / TPB), dim3(512), 0, stream>>>(x, wbuf, b, out_scores, out_idx);
}